// Round 18
// baseline (52.257 us; speedup 1.0000x reference)
//
#include <hip/hip_runtime.h>

#define NV 6890
#define NVP16 6912   // padded to 16
#define NJ 24
#define BATCH 512
#define NCOL 20670   // NV*3
#define NCOLP 20736  // 108*192 (also 1296*16)
#define KK 224       // 207 pose + 10 beta + 7 zero
#define JCH 864      // vert chunk for jreg stage A (8*864 >= 6890)
#define PSTR 104     // wave-private LDS pair-row stride (uints)
#define MTB 16       // batches per tile

typedef float f4 __attribute__((ext_vector_type(4)));
typedef float f32x4 __attribute__((ext_vector_type(4)));
typedef float f32x16 __attribute__((ext_vector_type(16)));
typedef short bf16x8 __attribute__((ext_vector_type(8)));
typedef unsigned short ushort8 __attribute__((ext_vector_type(8)));

// ws layout (bytes):
//   Abuf  ushort[512][224]        @ 0         (229376)
//   Bbuf  ushort[1296][7][512]    @ 229376    (9289728)  end 9519104   (fragment-major)
//   Amd2  ushort[256][2][512]     @ 9519104   (524288)   end 10043392  (32x32x16 A-frags)
//   part  float[24][8][33]        @ 10043392  (25344)    end 10068736
//   Wb2   ushort[216][2][512]     @ 10068736  (442368)   end 10511104  (32x32x16 B-frags)

__device__ __forceinline__ unsigned short bf16_rne(float x) {
  union { float f; unsigned u; } c; c.f = x;
  unsigned r = c.u + 0x7fffu + ((c.u >> 16) & 1u);
  return (unsigned short)(r >> 16);
}
__device__ __forceinline__ float bf16lo_f(unsigned u) {
  union { unsigned u; float f; } c; c.u = u << 16; return c.f;
}
__device__ __forceinline__ float bf16hi_f(unsigned u) {
  union { unsigned u; float f; } c; c.u = u & 0xFFFF0000u; return c.f;
}

// ---------------- K0: fused {jregA partials | B prep | W prep (32x32 frag)} ----------------
__global__ void k_pre(const float* __restrict__ Jreg, const float* __restrict__ vtemp,
                      const float* __restrict__ sdirs, const float* __restrict__ pdirs,
                      const float* __restrict__ wgt,
                      float* __restrict__ partial, unsigned short* __restrict__ Bbuf,
                      unsigned short* __restrict__ Wb2) {
  int bid = blockIdx.x;
  int tid = threadIdx.x;
  if (bid < 192) {
    int j = bid >> 3, bz = bid & 7;
    float acc[33];
#pragma unroll
    for (int i = 0; i < 33; ++i) acc[i] = 0.f;
    int v0 = bz * JCH;
    int v1 = v0 + JCH; if (v1 > NV) v1 = NV;
    for (int v = v0 + tid; v < v1; v += 256) {
      float w = Jreg[(size_t)j * NV + v];
      const float* vt = vtemp + (size_t)v * 3;
      acc[0] += w * vt[0]; acc[1] += w * vt[1]; acc[2] += w * vt[2];
      const float* sdv = sdirs + (size_t)v * 30;
#pragma unroll
      for (int t = 0; t < 30; ++t) acc[3 + t] += w * sdv[t];
    }
#pragma unroll
    for (int i = 0; i < 33; ++i) {
      float a = acc[i];
#pragma unroll
      for (int s = 32; s > 0; s >>= 1) a += __shfl_xor(a, s, 64);
      acc[i] = a;
    }
    __shared__ float red[4][34];
    int lane = tid & 63, wv = tid >> 6;
    if (lane == 0) {
#pragma unroll
      for (int i = 0; i < 33; ++i) red[wv][i] = acc[i];
    }
    __syncthreads();
    if (tid < 33) {
      float s = red[0][tid] + red[1][tid] + red[2][tid] + red[3][tid];
      partial[((size_t)j * 8 + bz) * 33 + tid] = s;
    }
    return;
  }
  int idx = (bid - 192) * 256 + tid;  // NCOLP*28 + NVP16*4 = 608256 = 2376*256
  if (idx < NCOLP * 28) {
    int n = idx / 28, k8 = idx % 28;
    int kc = k8 >> 2, h = k8 & 3;
    ushort8 o;
#pragma unroll
    for (int e = 0; e < 8; ++e) {
      int k = k8 * 8 + e;
      float v = 0.f;
      if (n < NCOL) {
        if (k < 207) v = pdirs[(size_t)n * 207 + k];
        else if (k < 217) v = sdirs[(size_t)n * 10 + (k - 207)];
      }
      o[e] = bf16_rne(v);
    }
    size_t dst = ((size_t)(n >> 4) * 7 + kc) * 512 + (size_t)(h * 16 + (n & 15)) * 8;
    *(ushort8*)(Bbuf + dst) = o;
  } else {
    int widx = idx - NCOLP * 28;
    int v = widx >> 2, q = widx & 3;
    ushort8 o = {0, 0, 0, 0, 0, 0, 0, 0};
    if (v < NV && q < 3) {
#pragma unroll
      for (int e = 0; e < 8; ++e) o[e] = bf16_rne(wgt[(size_t)v * 24 + q * 8 + e]);
    }
    int km = q >> 1;
    int lhalf = q & 1;
    size_t dst = ((size_t)(v >> 5) * 2 + km) * 512 + (size_t)((v & 31) + 32 * lhalf) * 8;
    *(ushort8*)(Wb2 + dst) = o;
  }
}

// ---------------- K1: joints/rodrigues/chain — 4 batches per 256-thread block ----------------
__global__ void k_batch(const float* __restrict__ pose, const float* __restrict__ beta,
                        const int* __restrict__ parent, const float* __restrict__ partial,
                        unsigned short* __restrict__ Abuf, unsigned short* __restrict__ Amd2) {
  int tid = threadIdx.x;
  int g = tid >> 6;      // sub-batch 0..3
  int j = tid & 63;
  int b = blockIdx.x * 4 + g;
  __shared__ float JS[NJ][33];
  __shared__ float jl[4][NJ][3];
  __shared__ float gl[4][NJ][16];

  {  // zero-fill this block's Amd2 (2 pairs x 2 km x 512 ushorts)
    ushort8 z = {0, 0, 0, 0, 0, 0, 0, 0};
    *(ushort8*)(Amd2 + (size_t)blockIdx.x * 2048 + tid * 8) = z;
  }

  for (int i = tid; i < NJ * 33; i += 256) {
    int jj = i / 33, q = i % 33;
    float s = 0.f;
#pragma unroll
    for (int bz = 0; bz < 8; ++bz) s += partial[((size_t)jj * 8 + bz) * 33 + q];
    JS[jj][q] = s;
  }
  __syncthreads();

  float bt[10];
#pragma unroll
  for (int t = 0; t < 10; ++t) bt[t] = beta[b * 10 + t];

  float R[9];
  float Jj[3] = {0.f, 0.f, 0.f};
  if (j < NJ) {
#pragma unroll
    for (int c = 0; c < 3; ++c) {
      float a = JS[j][c];
#pragma unroll
      for (int t = 0; t < 10; ++t) a += JS[j][3 + c * 10 + t] * bt[t];
      Jj[c] = a;
      jl[g][j][c] = a;
    }
    float rx = pose[b * 72 + j * 3 + 0];
    float ry = pose[b * 72 + j * 3 + 1];
    float rz = pose[b * 72 + j * 3 + 2];
    float theta = sqrtf(rx * rx + ry * ry + rz * rz) + 1e-8f;
    float inv = 1.f / theta;
    float ax = rx * inv, ay = ry * inv, az = rz * inv;
    float c = cosf(theta), s = sinf(theta), oc = 1.f - c;
    R[0] = c + oc * ax * ax;      R[1] = oc * ax * ay - s * az; R[2] = oc * ax * az + s * ay;
    R[3] = oc * ax * ay + s * az; R[4] = c + oc * ay * ay;      R[5] = oc * ay * az - s * ax;
    R[6] = oc * ax * az - s * ay; R[7] = oc * ay * az + s * ax; R[8] = c + oc * az * az;
  }
  __syncthreads();

  if (j >= 1 && j < NJ) {
    unsigned short* lr = Abuf + b * KK + (j - 1) * 9;
#pragma unroll
    for (int k = 0; k < 9; ++k)
      lr[k] = bf16_rne(R[k] - ((k == 0 || k == 4 || k == 8) ? 1.f : 0.f));
  }
  if (j >= 32 && j < 42) Abuf[b * KK + 207 + (j - 32)] = bf16_rne(bt[j - 32]);
  if (j >= 42 && j < 49) Abuf[b * KK + 207 + (j - 32)] = 0;

  if (j < NJ) {
    int par = (j == 0) ? 0 : parent[j - 1];
#pragma unroll
    for (int r = 0; r < 3; ++r) {
      gl[g][j][r * 4 + 0] = R[r * 3 + 0];
      gl[g][j][r * 4 + 1] = R[r * 3 + 1];
      gl[g][j][r * 4 + 2] = R[r * 3 + 2];
      gl[g][j][r * 4 + 3] = (j == 0) ? Jj[r] : Jj[r] - jl[g][par][r];
    }
  }
  __syncthreads();

  if (j < NJ) {
    int a[12];
    int n = 0, cur = j;
    while (cur != 0 && n < 12) { a[n++] = cur; cur = parent[cur - 1]; }
    float G[12];
#pragma unroll
    for (int r = 0; r < 3; ++r)
#pragma unroll
      for (int cc = 0; cc < 4; ++cc) G[r * 4 + cc] = gl[g][0][r * 4 + cc];
    for (int i = n - 1; i >= 0; --i) {
      const float* L = gl[g][a[i]];
      float C[12];
#pragma unroll
      for (int r = 0; r < 3; ++r) {
#pragma unroll
        for (int cc = 0; cc < 4; ++cc) {
          float sacc = (cc == 3) ? G[r * 4 + 3] : 0.f;
#pragma unroll
          for (int k = 0; k < 3; ++k) sacc += G[r * 4 + k] * L[k * 4 + cc];
          C[r * 4 + cc] = sacc;
        }
      }
#pragma unroll
      for (int k = 0; k < 12; ++k) G[k] = C[k];
    }
    float Aval[12];
#pragma unroll
    for (int r = 0; r < 3; ++r) {
      Aval[r * 4 + 0] = G[r * 4 + 0];
      Aval[r * 4 + 1] = G[r * 4 + 1];
      Aval[r * 4 + 2] = G[r * 4 + 2];
      Aval[r * 4 + 3] = G[r * 4 + 3] -
                        (G[r * 4 + 0] * jl[g][j][0] + G[r * 4 + 1] * jl[g][j][1] +
                         G[r * 4 + 2] * jl[g][j][2]);
    }
    // Amd2 fragment-major for 32x32x16 A-operand (bf16)
    int pair = b >> 1, odd = b & 1;
    int km = j >> 4, kl = j & 15;
    int lhalf = kl >> 3, e = kl & 7;
    unsigned short* base = Amd2 + ((size_t)pair * 2 + km) * 512;
#pragma unroll
    for (int r = 0; r < 3; ++r)
#pragma unroll
      for (int cc = 0; cc < 4; ++cc) {
        int row = odd * 16 + r * 4 + cc;
        base[(row + 32 * lhalf) * 8 + e] = bf16_rne(Aval[r * 4 + cc]);
      }
  }
}

// ---------------- K2: fused pose-blend GEMM + 32x32x16 MFMA skinning, BARRIER-FREE ----------------
// grid 3456 x 128 threads (2 waves). Tile: 192 cols x 16 batches.
// Wave w: phase-1 = 6 strips (96 cols = its 32 verts) x 1 m-tile,
// phase-2 = T for 32 verts x 8 batch-pairs via 32x32x16 MFMA.
__launch_bounds__(128, 5)
__global__ void k_gemmskin(const unsigned short* __restrict__ Abuf,
                           const unsigned short* __restrict__ Bbuf,
                           const float* __restrict__ vtemp,
                           const unsigned short* __restrict__ Amd2,
                           const unsigned short* __restrict__ Wb2,
                           float* __restrict__ out) {
  __shared__ unsigned vp[2 * 8 * PSTR];  // 6656 B, wave-private slices

  int bid = blockIdx.x;
  int lin = (bid & 7) * 432 + (bid >> 3);  // bijective over [0,3456)
  int bx = lin >> 5;
  int by = lin & 31;

  int tid = threadIdx.x;
  int w = tid >> 6, lane = tid & 63;
  int lo = lane & 15, hi = lane >> 4;
  int bb0 = by * MTB;
  unsigned* wvp = vp + w * 8 * PSTR;

  // ---- Phase 1: pose-blend GEMM, 6 strips of 16 cols per wave, single m-tile ----
  bf16x8 Af[7];
  {
    const unsigned short* arow = Abuf + (size_t)(bb0 + lo) * KK + hi * 8;
#pragma unroll
    for (int kc = 0; kc < 7; ++kc)
      Af[kc] = *(const bf16x8*)(arow + kc * 32);
  }

#pragma unroll
  for (int s = 0; s < 6; ++s) {
    const unsigned short* btile = Bbuf + ((size_t)(bx * 12 + w * 6 + s) * 7) * 512 + lane * 8;
    bf16x8 Bf[7];
#pragma unroll
    for (int kc = 0; kc < 7; ++kc) Bf[kc] = *(const bf16x8*)(btile + kc * 512);
    int gc = bx * 192 + w * 96 + s * 16 + lo;
    float vt = (gc < NCOL) ? vtemp[gc] : 0.f;
    f32x4 acc = {vt, vt, vt, vt};
#pragma unroll
    for (int kc = 0; kc < 7; ++kc)
      acc = __builtin_amdgcn_mfma_f32_16x16x32_bf16(Af[kc], Bf[kc], acc, 0, 0, 0);
#pragma unroll
    for (int rp = 0; rp < 2; ++rp) {
      unsigned pr = (unsigned)bf16_rne(acc[2 * rp]) |
                    ((unsigned)bf16_rne(acc[2 * rp + 1]) << 16);
      wvp[(hi * 2 + rp) * PSTR + s * 16 + lo] = pr;
    }
  }

  // ---- Phase 2 setup (no barrier; wave consumes only its own vp slice) ----
  int v = lane & 31, h32 = lane >> 5;
  int vg = bx * 64 + w * 32 + v;
  bool sok = vg < NV;
  int vt32 = bx * 2 + w;
  bf16x8 Wf0 = *(const bf16x8*)(Wb2 + ((size_t)vt32 * 2 + 0) * 512 + lane * 8);
  bf16x8 Wf1 = *(const bf16x8*)(Wb2 + ((size_t)vt32 * 2 + 1) * 512 + lane * 8);

  int gp0 = by * 8;
  bf16x8 A0c = *(const bf16x8*)(Amd2 + ((size_t)gp0 * 2 + 0) * 512 + lane * 8);
  bf16x8 A1c = *(const bf16x8*)(Amd2 + ((size_t)gp0 * 2 + 1) * 512 + lane * 8);

  // ---- Phase 2: 8 batch-pairs, rolling prefetch ----
#pragma unroll 4
  for (int p = 0; p < 8; ++p) {
    bf16x8 A0n, A1n;
    if (p < 7) {
      size_t t = ((size_t)(gp0 + p + 1)) * 2;
      A0n = *(const bf16x8*)(Amd2 + t * 512 + lane * 8);
      A1n = *(const bf16x8*)(Amd2 + (t + 1) * 512 + lane * 8);
    }
    unsigned ux = wvp[p * PSTR + 3 * v + 0];
    unsigned uy = wvp[p * PSTR + 3 * v + 1];
    unsigned uz = wvp[p * PSTR + 3 * v + 2];

    f32x16 acc = {0.f, 0.f, 0.f, 0.f, 0.f, 0.f, 0.f, 0.f,
                  0.f, 0.f, 0.f, 0.f, 0.f, 0.f, 0.f, 0.f};
    acc = __builtin_amdgcn_mfma_f32_32x32x16_bf16(A0c, Wf0, acc, 0, 0, 0);
    acc = __builtin_amdgcn_mfma_f32_32x32x16_bf16(A1c, Wf1, acc, 0, 0, 0);

    float xe = bf16lo_f(ux), ye = bf16lo_f(uy), ze = bf16lo_f(uz);
    float xo = bf16hi_f(ux), yo = bf16hi_f(uy), zo = bf16hi_f(uz);
    float oA = acc[0] * xe + acc[1] * ye + acc[2] * ze + acc[3];
    float oB = acc[4] * xe + acc[5] * ye + acc[6] * ze + acc[7];
    float oC = acc[8] * xo + acc[9] * yo + acc[10] * zo + acc[11];
    float oD = acc[12] * xo + acc[13] * yo + acc[14] * zo + acc[15];

    if (sok) {
      size_t be = (size_t)(bb0 + 2 * p) * NV + vg;
      size_t bo = be + NV;
      out[be * 3 + h32] = oA;
      out[bo * 3 + h32] = oC;
      if (h32 == 0) {
        out[be * 3 + 2] = oB;
        out[bo * 3 + 2] = oD;
      }
    }
    A0c = A0n; A1c = A1n;
  }
}

extern "C" void kernel_launch(void* const* d_in, const int* in_sizes, int n_in,
                              void* d_out, int out_size, void* d_ws, size_t ws_size,
                              hipStream_t stream) {
  const float* pose   = (const float*)d_in[0];
  const float* beta   = (const float*)d_in[1];
  const float* vtemp  = (const float*)d_in[2];
  const float* sdirs  = (const float*)d_in[3];
  const float* pdirs  = (const float*)d_in[4];
  const float* Jreg   = (const float*)d_in[5];
  const float* wgt    = (const float*)d_in[6];
  const int*   parent = (const int*)d_in[7];
  float* out = (float*)d_out;

  char* wsb = (char*)d_ws;
  unsigned short* Abuf = (unsigned short*)wsb;
  unsigned short* Bbuf = (unsigned short*)(wsb + 229376);
  unsigned short* Amd2 = (unsigned short*)(wsb + 9519104);
  float* part          = (float*)(wsb + 10043392);
  unsigned short* Wb2  = (unsigned short*)(wsb + 10068736);

  hipLaunchKernelGGL(k_pre, dim3(192 + (NCOLP * 28 + NVP16 * 4) / 256), dim3(256), 0, stream,
                     Jreg, vtemp, sdirs, pdirs, wgt, part, Bbuf, Wb2);
  hipLaunchKernelGGL(k_batch, dim3(BATCH / 4), dim3(256), 0, stream, pose, beta, parent, part,
                     Abuf, Amd2);
  hipLaunchKernelGGL(k_gemmskin, dim3(3456), dim3(128), 0, stream,
                     Abuf, Bbuf, vtemp, Amd2, Wb2, out);
}

// Round 19
// 48.388 us; speedup vs baseline: 1.0800x; 1.0800x over previous
//
#include <hip/hip_runtime.h>

#define NV 6890
#define NVP16 6912   // padded to 16
#define NJ 24
#define BATCH 512
#define NCOL 20670   // NV*3
#define NCOLP 20736  // 108*192 (also 1296*16)
#define KK 224       // 207 pose + 10 beta + 7 zero
#define JCH 864      // vert chunk for jreg stage A (8*864 >= 6890)
#define PSTR 104     // wave-private LDS pair-row stride (uints)
#define MTB 32       // batches per tile

typedef float f4 __attribute__((ext_vector_type(4)));
typedef float f32x4 __attribute__((ext_vector_type(4)));
typedef float f32x16 __attribute__((ext_vector_type(16)));
typedef short bf16x8 __attribute__((ext_vector_type(8)));
typedef unsigned short ushort8 __attribute__((ext_vector_type(8)));

// ws layout (bytes):
//   Abuf  ushort[512][224]        @ 0         (229376)
//   Bbuf  ushort[1296][7][512]    @ 229376    (9289728)  end 9519104   (fragment-major)
//   Amd2  ushort[256][2][512]     @ 9519104   (524288)   end 10043392  (32x32x16 A-frags)
//   part  float[24][8][33]        @ 10043392  (25344)    end 10068736
//   Wb2   ushort[216][2][512]     @ 10068736  (442368)   end 10511104  (32x32x16 B-frags)

__device__ __forceinline__ unsigned short bf16_rne(float x) {
  union { float f; unsigned u; } c; c.f = x;
  unsigned r = c.u + 0x7fffu + ((c.u >> 16) & 1u);
  return (unsigned short)(r >> 16);
}
__device__ __forceinline__ float bf16lo_f(unsigned u) {
  union { unsigned u; float f; } c; c.u = u << 16; return c.f;
}
__device__ __forceinline__ float bf16hi_f(unsigned u) {
  union { unsigned u; float f; } c; c.u = u & 0xFFFF0000u; return c.f;
}

// ---------------- K0: fused {jregA partials | B prep | W prep (32x32 frag)} ----------------
__global__ void k_pre(const float* __restrict__ Jreg, const float* __restrict__ vtemp,
                      const float* __restrict__ sdirs, const float* __restrict__ pdirs,
                      const float* __restrict__ wgt,
                      float* __restrict__ partial, unsigned short* __restrict__ Bbuf,
                      unsigned short* __restrict__ Wb2) {
  int bid = blockIdx.x;
  int tid = threadIdx.x;
  if (bid < 192) {
    int j = bid >> 3, bz = bid & 7;
    float acc[33];
#pragma unroll
    for (int i = 0; i < 33; ++i) acc[i] = 0.f;
    int v0 = bz * JCH;
    int v1 = v0 + JCH; if (v1 > NV) v1 = NV;
    for (int v = v0 + tid; v < v1; v += 256) {
      float w = Jreg[(size_t)j * NV + v];
      const float* vt = vtemp + (size_t)v * 3;
      acc[0] += w * vt[0]; acc[1] += w * vt[1]; acc[2] += w * vt[2];
      const float* sdv = sdirs + (size_t)v * 30;
#pragma unroll
      for (int t = 0; t < 30; ++t) acc[3 + t] += w * sdv[t];
    }
#pragma unroll
    for (int i = 0; i < 33; ++i) {
      float a = acc[i];
#pragma unroll
      for (int s = 32; s > 0; s >>= 1) a += __shfl_xor(a, s, 64);
      acc[i] = a;
    }
    __shared__ float red[4][34];
    int lane = tid & 63, wv = tid >> 6;
    if (lane == 0) {
#pragma unroll
      for (int i = 0; i < 33; ++i) red[wv][i] = acc[i];
    }
    __syncthreads();
    if (tid < 33) {
      float s = red[0][tid] + red[1][tid] + red[2][tid] + red[3][tid];
      partial[((size_t)j * 8 + bz) * 33 + tid] = s;
    }
    return;
  }
  int idx = (bid - 192) * 256 + tid;  // NCOLP*28 + NVP16*4 = 608256 = 2376*256
  if (idx < NCOLP * 28) {
    int n = idx / 28, k8 = idx % 28;
    int kc = k8 >> 2, h = k8 & 3;
    ushort8 o;
#pragma unroll
    for (int e = 0; e < 8; ++e) {
      int k = k8 * 8 + e;
      float v = 0.f;
      if (n < NCOL) {
        if (k < 207) v = pdirs[(size_t)n * 207 + k];
        else if (k < 217) v = sdirs[(size_t)n * 10 + (k - 207)];
      }
      o[e] = bf16_rne(v);
    }
    size_t dst = ((size_t)(n >> 4) * 7 + kc) * 512 + (size_t)(h * 16 + (n & 15)) * 8;
    *(ushort8*)(Bbuf + dst) = o;
  } else {
    // Wb2 fragment-major for 32x32x16 B-operand: element (vert v, joint j):
    //   vt=v>>5, km=j>>4, lane=(v&31)+32*((j&15)>>3), e=j&7
    int widx = idx - NCOLP * 28;
    int v = widx >> 2, q = widx & 3;
    ushort8 o = {0, 0, 0, 0, 0, 0, 0, 0};
    if (v < NV && q < 3) {
#pragma unroll
      for (int e = 0; e < 8; ++e) o[e] = bf16_rne(wgt[(size_t)v * 24 + q * 8 + e]);
    }
    int km = q >> 1;                  // q=0,1 -> km0 ; q=2,3 -> km1
    int lhalf = q & 1;                // lanes +32 for q odd
    size_t dst = ((size_t)(v >> 5) * 2 + km) * 512 + (size_t)((v & 31) + 32 * lhalf) * 8;
    *(ushort8*)(Wb2 + dst) = o;
  }
}

// ---------------- K1: joints/rodrigues/chain — 4 batches per 256-thread block ----------------
__global__ void k_batch(const float* __restrict__ pose, const float* __restrict__ beta,
                        const int* __restrict__ parent, const float* __restrict__ partial,
                        unsigned short* __restrict__ Abuf, unsigned short* __restrict__ Amd2) {
  int tid = threadIdx.x;
  int g = tid >> 6;      // sub-batch 0..3
  int j = tid & 63;
  int b = blockIdx.x * 4 + g;
  __shared__ float JS[NJ][33];
  __shared__ float jl[4][NJ][3];
  __shared__ float gl[4][NJ][16];

  {  // zero-fill this block's 2 pairs x 2 km x 512 ushorts
    ushort8 z = {0, 0, 0, 0, 0, 0, 0, 0};
    *(ushort8*)(Amd2 + (size_t)blockIdx.x * 2048 + tid * 8) = z;
  }

  for (int i = tid; i < NJ * 33; i += 256) {
    int jj = i / 33, q = i % 33;
    float s = 0.f;
#pragma unroll
    for (int bz = 0; bz < 8; ++bz) s += partial[((size_t)jj * 8 + bz) * 33 + q];
    JS[jj][q] = s;
  }
  __syncthreads();

  float bt[10];
#pragma unroll
  for (int t = 0; t < 10; ++t) bt[t] = beta[b * 10 + t];

  float R[9];
  float Jj[3] = {0.f, 0.f, 0.f};
  if (j < NJ) {
#pragma unroll
    for (int c = 0; c < 3; ++c) {
      float a = JS[j][c];
#pragma unroll
      for (int t = 0; t < 10; ++t) a += JS[j][3 + c * 10 + t] * bt[t];
      Jj[c] = a;
      jl[g][j][c] = a;
    }
    float rx = pose[b * 72 + j * 3 + 0];
    float ry = pose[b * 72 + j * 3 + 1];
    float rz = pose[b * 72 + j * 3 + 2];
    float theta = sqrtf(rx * rx + ry * ry + rz * rz) + 1e-8f;
    float inv = 1.f / theta;
    float ax = rx * inv, ay = ry * inv, az = rz * inv;
    float c = cosf(theta), s = sinf(theta), oc = 1.f - c;
    R[0] = c + oc * ax * ax;      R[1] = oc * ax * ay - s * az; R[2] = oc * ax * az + s * ay;
    R[3] = oc * ax * ay + s * az; R[4] = c + oc * ay * ay;      R[5] = oc * ay * az - s * ax;
    R[6] = oc * ax * az - s * ay; R[7] = oc * ay * az + s * ax; R[8] = c + oc * az * az;
  }
  __syncthreads();

  if (j >= 1 && j < NJ) {
    unsigned short* lr = Abuf + b * KK + (j - 1) * 9;
#pragma unroll
    for (int k = 0; k < 9; ++k)
      lr[k] = bf16_rne(R[k] - ((k == 0 || k == 4 || k == 8) ? 1.f : 0.f));
  }
  if (j >= 32 && j < 42) Abuf[b * KK + 207 + (j - 32)] = bf16_rne(bt[j - 32]);
  if (j >= 42 && j < 49) Abuf[b * KK + 207 + (j - 32)] = 0;

  if (j < NJ) {
    int par = (j == 0) ? 0 : parent[j - 1];
#pragma unroll
    for (int r = 0; r < 3; ++r) {
      gl[g][j][r * 4 + 0] = R[r * 3 + 0];
      gl[g][j][r * 4 + 1] = R[r * 3 + 1];
      gl[g][j][r * 4 + 2] = R[r * 3 + 2];
      gl[g][j][r * 4 + 3] = (j == 0) ? Jj[r] : Jj[r] - jl[g][par][r];
    }
  }
  __syncthreads();

  if (j < NJ) {
    int a[12];
    int n = 0, cur = j;
    while (cur != 0 && n < 12) { a[n++] = cur; cur = parent[cur - 1]; }
    float G[12];
#pragma unroll
    for (int r = 0; r < 3; ++r)
#pragma unroll
      for (int cc = 0; cc < 4; ++cc) G[r * 4 + cc] = gl[g][0][r * 4 + cc];
    for (int i = n - 1; i >= 0; --i) {
      const float* L = gl[g][a[i]];
      float C[12];
#pragma unroll
      for (int r = 0; r < 3; ++r) {
#pragma unroll
        for (int cc = 0; cc < 4; ++cc) {
          float sacc = (cc == 3) ? G[r * 4 + 3] : 0.f;
#pragma unroll
          for (int k = 0; k < 3; ++k) sacc += G[r * 4 + k] * L[k * 4 + cc];
          C[r * 4 + cc] = sacc;
        }
      }
#pragma unroll
      for (int k = 0; k < 12; ++k) G[k] = C[k];
    }
    float Aval[12];
#pragma unroll
    for (int r = 0; r < 3; ++r) {
      Aval[r * 4 + 0] = G[r * 4 + 0];
      Aval[r * 4 + 1] = G[r * 4 + 1];
      Aval[r * 4 + 2] = G[r * 4 + 2];
      Aval[r * 4 + 3] = G[r * 4 + 3] -
                        (G[r * 4 + 0] * jl[g][j][0] + G[r * 4 + 1] * jl[g][j][1] +
                         G[r * 4 + 2] * jl[g][j][2]);
    }
    // Amd2 fragment-major for 32x32x16 A-operand: element (row, k=j):
    //   pair=b>>1, row=(b&1)*16 + r*4+cc, km=j>>4, lane=row+32*((j&15)>>3), e=j&7
    int pair = b >> 1, odd = b & 1;
    int km = j >> 4, kl = j & 15;
    int lhalf = kl >> 3, e = kl & 7;
    unsigned short* base = Amd2 + ((size_t)pair * 2 + km) * 512;
#pragma unroll
    for (int r = 0; r < 3; ++r)
#pragma unroll
      for (int cc = 0; cc < 4; ++cc) {
        int row = odd * 16 + r * 4 + cc;
        base[(row + 32 * lhalf) * 8 + e] = bf16_rne(Aval[r * 4 + cc]);
      }
  }
}

// ---------------- K2: fused pose-blend GEMM + 32x32x16 MFMA skinning, BARRIER-FREE ----------------
// grid 1728 x 128 threads (2 waves). Wave w: phase-1 = 6 strips (96 cols = its 32 verts),
// phase-2 = T for 32 verts x 16 batch-pairs via 32x32x16 MFMA (2 batches per A-tile).
__launch_bounds__(128, 4)
__global__ void k_gemmskin(const unsigned short* __restrict__ Abuf,
                           const unsigned short* __restrict__ Bbuf,
                           const float* __restrict__ vtemp,
                           const unsigned short* __restrict__ Amd2,
                           const unsigned short* __restrict__ Wb2,
                           float* __restrict__ out) {
  __shared__ unsigned vp[2 * 16 * PSTR];  // 13312 B, wave-private slices

  int bid = blockIdx.x;
  int lin = (bid & 7) * 216 + (bid >> 3);
  int bx = lin >> 4;
  int by = lin & 15;

  int tid = threadIdx.x;
  int w = tid >> 6, lane = tid & 63;
  int lo = lane & 15, hi = lane >> 4;
  int bb0 = by * MTB;
  unsigned* wvp = vp + w * 16 * PSTR;

  // ---- Phase 1: pose-blend GEMM, 6 strips of 16 cols per wave ----
  bf16x8 Af[2][7];
#pragma unroll
  for (int mt = 0; mt < 2; ++mt) {
    const unsigned short* arow = Abuf + (size_t)(bb0 + mt * 16 + lo) * KK + hi * 8;
#pragma unroll
    for (int kc = 0; kc < 7; ++kc)
      Af[mt][kc] = *(const bf16x8*)(arow + kc * 32);
  }

#pragma unroll
  for (int s = 0; s < 6; ++s) {
    const unsigned short* btile = Bbuf + ((size_t)(bx * 12 + w * 6 + s) * 7) * 512 + lane * 8;
    bf16x8 Bf[7];
#pragma unroll
    for (int kc = 0; kc < 7; ++kc) Bf[kc] = *(const bf16x8*)(btile + kc * 512);
    int gc = bx * 192 + w * 96 + s * 16 + lo;
    float vt = (gc < NCOL) ? vtemp[gc] : 0.f;
#pragma unroll
    for (int mt = 0; mt < 2; ++mt) {
      f32x4 acc = {vt, vt, vt, vt};
#pragma unroll
      for (int kc = 0; kc < 7; ++kc)
        acc = __builtin_amdgcn_mfma_f32_16x16x32_bf16(Af[mt][kc], Bf[kc], acc, 0, 0, 0);
#pragma unroll
      for (int rp = 0; rp < 2; ++rp) {
        unsigned pr = (unsigned)bf16_rne(acc[2 * rp]) |
                      ((unsigned)bf16_rne(acc[2 * rp + 1]) << 16);
        wvp[(mt * 8 + hi * 2 + rp) * PSTR + s * 16 + lo] = pr;
      }
    }
  }

  // ---- Phase 2 setup (no barrier; wave consumes only its own vp slice) ----
  int v = lane & 31, h32 = lane >> 5;
  int vg = bx * 64 + w * 32 + v;
  bool sok = vg < NV;
  int vt32 = bx * 2 + w;
  bf16x8 Wf0 = *(const bf16x8*)(Wb2 + ((size_t)vt32 * 2 + 0) * 512 + lane * 8);
  bf16x8 Wf1 = *(const bf16x8*)(Wb2 + ((size_t)vt32 * 2 + 1) * 512 + lane * 8);

  int gp0 = by * 16;
  bf16x8 A0c = *(const bf16x8*)(Amd2 + ((size_t)gp0 * 2 + 0) * 512 + lane * 8);
  bf16x8 A1c = *(const bf16x8*)(Amd2 + ((size_t)gp0 * 2 + 1) * 512 + lane * 8);

  // ---- Phase 2: 16 batch-pairs, rolling prefetch ----
#pragma unroll 4
  for (int p = 0; p < 16; ++p) {
    bf16x8 A0n, A1n;
    if (p < 15) {
      size_t t = ((size_t)(gp0 + p + 1)) * 2;
      A0n = *(const bf16x8*)(Amd2 + t * 512 + lane * 8);
      A1n = *(const bf16x8*)(Amd2 + (t + 1) * 512 + lane * 8);
    }
    unsigned ux = wvp[p * PSTR + 3 * v + 0];
    unsigned uy = wvp[p * PSTR + 3 * v + 1];
    unsigned uz = wvp[p * PSTR + 3 * v + 2];

    f32x16 acc = {0.f, 0.f, 0.f, 0.f, 0.f, 0.f, 0.f, 0.f,
                  0.f, 0.f, 0.f, 0.f, 0.f, 0.f, 0.f, 0.f};
    acc = __builtin_amdgcn_mfma_f32_32x32x16_bf16(A0c, Wf0, acc, 0, 0, 0);
    acc = __builtin_amdgcn_mfma_f32_32x32x16_bf16(A1c, Wf1, acc, 0, 0, 0);

    float xe = bf16lo_f(ux), ye = bf16lo_f(uy), ze = bf16lo_f(uz);
    float xo = bf16hi_f(ux), yo = bf16hi_f(uy), zo = bf16hi_f(uz);
    // lane holds (for its h32): rows {0-3,8-11} (+4*h32) of even batch and {16-19,24-27}(+4*h32) odd
    float oA = acc[0] * xe + acc[1] * ye + acc[2] * ze + acc[3];    // even, comp h32 (x or y)
    float oB = acc[4] * xe + acc[5] * ye + acc[6] * ze + acc[7];    // even, comp 2 (h32=0 only)
    float oC = acc[8] * xo + acc[9] * yo + acc[10] * zo + acc[11];  // odd, comp h32
    float oD = acc[12] * xo + acc[13] * yo + acc[14] * zo + acc[15];// odd, comp 2 (h32=0 only)

    if (sok) {
      size_t be = (size_t)(bb0 + 2 * p) * NV + vg;
      size_t bo = be + NV;
      out[be * 3 + h32] = oA;
      out[bo * 3 + h32] = oC;
      if (h32 == 0) {
        out[be * 3 + 2] = oB;
        out[bo * 3 + 2] = oD;
      }
    }
    A0c = A0n; A1c = A1n;
  }
}

extern "C" void kernel_launch(void* const* d_in, const int* in_sizes, int n_in,
                              void* d_out, int out_size, void* d_ws, size_t ws_size,
                              hipStream_t stream) {
  const float* pose   = (const float*)d_in[0];
  const float* beta   = (const float*)d_in[1];
  const float* vtemp  = (const float*)d_in[2];
  const float* sdirs  = (const float*)d_in[3];
  const float* pdirs  = (const float*)d_in[4];
  const float* Jreg   = (const float*)d_in[5];
  const float* wgt    = (const float*)d_in[6];
  const int*   parent = (const int*)d_in[7];
  float* out = (float*)d_out;

  char* wsb = (char*)d_ws;
  unsigned short* Abuf = (unsigned short*)wsb;
  unsigned short* Bbuf = (unsigned short*)(wsb + 229376);
  unsigned short* Amd2 = (unsigned short*)(wsb + 9519104);
  float* part          = (float*)(wsb + 10043392);
  unsigned short* Wb2  = (unsigned short*)(wsb + 10068736);

  hipLaunchKernelGGL(k_pre, dim3(192 + (NCOLP * 28 + NVP16 * 4) / 256), dim3(256), 0, stream,
                     Jreg, vtemp, sdirs, pdirs, wgt, part, Bbuf, Wb2);
  hipLaunchKernelGGL(k_batch, dim3(BATCH / 4), dim3(256), 0, stream, pose, beta, parent, part,
                     Abuf, Amd2);
  hipLaunchKernelGGL(k_gemmskin, dim3(1728), dim3(128), 0, stream,
                     Abuf, Bbuf, vtemp, Amd2, Wb2, out);
}